// Round 3
// baseline (221.339 us; speedup 1.0000x reference)
//
#include <hip/hip_runtime.h>
#include <hip/hip_bf16.h>
#include <stdint.h>

// y[c,k] = sum_{a,b} E1[k,a] * Xc[c,a,b] * E2[k,b],  Xc = C*x, E = exp(i*angle*g)
// GEMM: tmp[a, 2k+comp] = A'[a,:] @ B'[:, 2k+comp]
//   A' = [Re(Xc) | Im(Xc)]  (256 x 512 per c)
//   B'[b,2k]=Er, B'[256+b,2k]=-Ei, B'[b,2k+1]=Ei, B'[256+b,2k+1]=Er
// Epilogue: y[c,k] = sum_a E1[k,a] (*) tmp[a,k]  (complex), * w[k%512]
//
// R3 structure: A fragments load global->register directly (A is 2MB,
// L2-resident; LDS round-trip for A had zero reuse). Only B goes through
// LDS (multicast to 4 waves), chunk-XOR swizzled (R2: conflicts 2e7 -> 0).
// 256x64 tile, acc 4x4 (64 AGPR) keeps unified regs ~<170 -> 3 waves/SIMD.

#define NKTOT 17408
#define NBLK_K 544   // 17408 / 32 k's per block
#define LDA 512
#define LDBT 512

typedef short bf16x8 __attribute__((ext_vector_type(8)));
typedef float f32x4 __attribute__((ext_vector_type(4)));

__device__ __forceinline__ unsigned short f2bf(float f) {
  unsigned int u = __builtin_bit_cast(unsigned int, f);
  u += 0x7FFFu + ((u >> 16) & 1u);
  return (unsigned short)(u >> 16);
}
__device__ __forceinline__ float bf2f(unsigned int lo16) {
  return __builtin_bit_cast(float, lo16 << 16);
}
__device__ __forceinline__ unsigned int pkbf(float x, float y) {
  return (unsigned int)f2bf(x) | ((unsigned int)f2bf(y) << 16);
}

__device__ __forceinline__ void async_copy16(void* lds, const void* g) {
  __builtin_amdgcn_global_load_lds(
      (const __attribute__((address_space(1))) unsigned int*)g,
      (__attribute__((address_space(3))) unsigned int*)lds, 16, 0, 0);
}

// Fused packing: blocks [0, NKTOT) do E2/E1 tables for one k each,
// blocks [NKTOT, NKTOT+2048) do A' = [Re|Im](C*x).
__global__ __launch_bounds__(256) void pack_all(
    const float* __restrict__ input_r, const float* __restrict__ C_r,
    const float* __restrict__ angle,
    unsigned short* __restrict__ Apack, unsigned short* __restrict__ BT,
    unsigned int* __restrict__ E1tab)
{
  int bk = blockIdx.x;
  if (bk < NKTOT) {
    int k = bk;
    int lt = threadIdx.x & 127;   // handles b = 2*lt, 2*lt+1
    int half = threadIdx.x >> 7;  // 0: E2 (angle t), 1: E1 (angle s)
    float ang = angle[k * 2 + (half ? 0 : 1)];
    int b0 = 2 * lt;
    float g0 = (float)(b0 - 128);
    float s0, c0, s1, c1;
    __sincosf(ang * g0, &s0, &c0);
    __sincosf(ang * (g0 + 1.0f), &s1, &c1);
    if (half == 0) {
      size_t r0 = (size_t)(2 * k) * LDBT;
      *(unsigned int*)(BT + r0 + b0)              = pkbf(c0, c1);
      *(unsigned int*)(BT + r0 + 256 + b0)        = pkbf(-s0, -s1);
      *(unsigned int*)(BT + r0 + LDBT + b0)       = pkbf(s0, s1);
      *(unsigned int*)(BT + r0 + LDBT + 256 + b0) = pkbf(c0, c1);
    } else {
      uint2 e;
      e.x = pkbf(c0, s0);
      e.y = pkbf(c1, s1);
      *(uint2*)(E1tab + (size_t)k * 256 + b0) = e;
    }
  } else {
    int tid = (bk - NKTOT) * 256 + threadIdx.x;
    int b = tid & 255;
    int a = (tid >> 8) & 255;
    int c = tid >> 16;
    float xr = input_r[(a * 256 + b) * 2 + 0];
    float xi = input_r[(a * 256 + b) * 2 + 1];
    size_t ci0 = ((size_t)(c * 256 + a) * 256 + b) * 2;
    float cr = C_r[ci0 + 0];
    float ci = C_r[ci0 + 1];
    size_t base = (size_t)c * (256 * LDA) + (size_t)a * LDA;
    Apack[base + b] = f2bf(cr * xr - ci * xi);
    Apack[base + 256 + b] = f2bf(cr * xi + ci * xr);
  }
}

__global__ __launch_bounds__(256, 3) void gemm_fused(
    const unsigned short* __restrict__ Apack,
    const unsigned short* __restrict__ BT,
    const unsigned int* __restrict__ E1tab,
    const float* __restrict__ wvec,
    float* __restrict__ out)
{
  __shared__ unsigned short Bs[64 * 64];  // 8 KB, swizzled 16B slots
  __shared__ float wavecol[4][64];

  // XCD-aware decode: bx%8 == kt%8 groups the 8 c-blocks of one kt on one
  // XCD so its L2 serves the B/E1 tiles once (R2: FETCH 127 -> 42 MB).
  const int bx = blockIdx.x;
  const int c = (bx >> 3) & 7;
  const int kt = (bx >> 6) * 8 + (bx & 7);
  const int kt0 = kt * 32;  // 32 k's (64 GEMM cols) per block
  const int tid = threadIdx.x;
  const int w = tid >> 6;
  const int l = tid & 63;
  const int lhi = l >> 4;
  const int llo = l & 15;
  const int lr = l >> 3;                     // staging row within 8-row chunk
  const int lcs = ((l & 7) ^ (l >> 3)) * 8;  // staging swizzled source chunk

  const unsigned short* Aw =
      Apack + (size_t)c * (256 * LDA) + (size_t)(w * 64 + llo) * LDA + lhi * 8;
  const unsigned short* Bbase = BT + (size_t)(kt0 * 2) * LDBT;

  f32x4 acc[4][4];
#pragma unroll
  for (int i = 0; i < 4; ++i)
#pragma unroll
    for (int j = 0; j < 4; ++j) {
      f32x4 z = {0.f, 0.f, 0.f, 0.f};
      acc[i][j] = z;
    }

  // A fragment prefetch pipeline (distance: one kf phase = 16 MFMAs)
  bf16x8 af[4];
#pragma unroll
  for (int fi = 0; fi < 4; ++fi)
    af[fi] = *(const bf16x8*)(Aw + fi * (16 * LDA));
  int kcol = 0;

  for (int kk = 0; kk < 512; kk += 64) {
    // stage Bs: 64 rows x 64 cols = 8 chunks of 1KB; wave w does 2
#pragma unroll
    for (int i = 0; i < 2; ++i) {
      int row0 = (w * 2 + i) * 8;
      async_copy16(&Bs[row0 * 64], Bbase + (size_t)(row0 + lr) * LDBT + kk + lcs);
    }
    __syncthreads();
#pragma unroll
    for (int kf = 0; kf < 2; ++kf) {
      const int soff = ((kf * 4 + lhi) ^ (llo & 7)) * 8;
      bf16x8 bfr[4];
#pragma unroll
      for (int fj = 0; fj < 4; ++fj)
        bfr[fj] = *(const bf16x8*)&Bs[(fj * 16 + llo) * 64 + soff];
      const int nkcol = (kcol + 32) & 511;
      bf16x8 afn[4];
#pragma unroll
      for (int fi = 0; fi < 4; ++fi)
        afn[fi] = *(const bf16x8*)(Aw + fi * (16 * LDA) + nkcol);
#pragma unroll
      for (int fi = 0; fi < 4; ++fi)
#pragma unroll
        for (int fj = 0; fj < 4; ++fj)
          acc[fi][fj] = __builtin_amdgcn_mfma_f32_16x16x32_bf16(
              af[fi], bfr[fj], acc[fi][fj], 0, 0, 0);
#pragma unroll
      for (int fi = 0; fi < 4; ++fi) af[fi] = afn[fi];
      kcol = nkcol;
    }
    __syncthreads();
  }

  // Epilogue: y[c,k] = sum_a E1 (*) tmp; wave w owns rows a in [w*64,w*64+64)
  // col = fj*16 + llo in [0,64); even col = Re, odd = Im of k = kt0 + col/2
#pragma unroll
  for (int fj = 0; fj < 4; ++fj) {
    const int col = fj * 16 + llo;
    const int k = kt0 + (col >> 1);
    const float sign = (col & 1) ? 1.f : -1.f;
    float sum = 0.f;
    const unsigned int* e1base = E1tab + (size_t)k * 256 + w * 64 + lhi * 4;
#pragma unroll
    for (int fi = 0; fi < 4; ++fi) {
      uint4 e4 = *(const uint4*)(e1base + fi * 16);
      unsigned int ev[4] = {e4.x, e4.y, e4.z, e4.w};
#pragma unroll
      for (int r = 0; r < 4; ++r) {
        float v = acc[fi][fj][r];        // this comp at (a, k)
        float p = __shfl_xor(v, 1, 64);  // partner comp, same (a, k)
        float er = bf2f(ev[r] & 0xFFFFu);
        float ei = bf2f(ev[r] >> 16);
        sum += er * v + sign * ei * p;   // even: er*tr - ei*ti; odd: er*ti + ei*tr
      }
    }
    sum += __shfl_xor(sum, 16, 64);
    sum += __shfl_xor(sum, 32, 64);
    if (lhi == 0) wavecol[w][col] = sum;
  }
  __syncthreads();
  if (tid < 64) {
    float sv = wavecol[0][tid] + wavecol[1][tid] + wavecol[2][tid] + wavecol[3][tid];
    int k = kt0 + (tid >> 1);
    out[((size_t)c * NKTOT + k) * 2 + (tid & 1)] = sv * wvec[k & 511];
  }
}

extern "C" void kernel_launch(void* const* d_in, const int* in_sizes, int n_in,
                              void* d_out, int out_size, void* d_ws, size_t ws_size,
                              hipStream_t stream) {
  const float* input_r = (const float*)d_in[0];  // (256,256,2)
  const float* C_r     = (const float*)d_in[1];  // (8,256,256,2)
  const float* wvec    = (const float*)d_in[2];  // (512,)
  const float* angle   = (const float*)d_in[3];  // (17408,2)
  float* out = (float*)d_out;                    // (8,17408,2)

  // workspace: A' (2MB) | B'T (34MB) | E1tab (17MB)
  unsigned short* Apack = (unsigned short*)d_ws;
  unsigned short* BT    = (unsigned short*)((char*)d_ws + (size_t)2097152);
  unsigned int*   E1tab = (unsigned int*)((char*)d_ws + (size_t)2097152 + 35651584);

  pack_all<<<NKTOT + 2048, 256, 0, stream>>>(input_r, C_r, angle, Apack, BT, E1tab);
  gemm_fused<<<8 * NBLK_K, 256, 0, stream>>>(Apack, BT, E1tab, wvec, out);
}

// Round 4
// 167.089 us; speedup vs baseline: 1.3247x; 1.3247x over previous
//
#include <hip/hip_runtime.h>
#include <hip/hip_bf16.h>
#include <stdint.h>

// y[c,k] = sum_{a,b} E1[k,a] * Xc[c,a,b] * E2[k,b],  Xc = C*x, E = exp(i*angle*g)
// GEMM: tmp[a, 2k+comp] = A'[a,:] @ B'[:, 2k+comp]
//   A' = [Re(Xc) | Im(Xc)]  (256 x 512 per c)
//   B'[b,2k]=Er, B'[256+b,2k]=-Ei, B'[b,2k+1]=Ei, B'[256+b,2k+1]=Er
// Epilogue: y[c,k] = sum_a E1[k,a] (*) tmp[a,k]  (complex), * w[k%512]
//
// R4: A' is packed in MFMA-fragment-native order
//   Afrag[c][rg=row/16][kc=k/8][llo=row%16][j=k%8]
// so a wave's A-fragment load is one contiguous, fully-coalesced 1 KB
// global load (R3's failure was this load as a 64-line gather -> 4x L2
// amplification). A never touches LDS (zero reuse there); only B is
// LDS-staged (multicast x4 waves), chunk-XOR swizzled (R2: conflicts -> 0).
// acc 4x4 (64 AGPR) + 9.2 KB LDS -> 3 blocks/CU. c = bx&7 pins each c's
// 2 MB A-slab to one XCD's L2; B/E1 are L3-resident after first pass.

#define NKTOT 17408
#define NBLK_K 544   // 17408 / 32 k's per block
#define LDBT 512

typedef short bf16x8 __attribute__((ext_vector_type(8)));
typedef float f32x4 __attribute__((ext_vector_type(4)));

__device__ __forceinline__ unsigned short f2bf(float f) {
  unsigned int u = __builtin_bit_cast(unsigned int, f);
  u += 0x7FFFu + ((u >> 16) & 1u);
  return (unsigned short)(u >> 16);
}
__device__ __forceinline__ float bf2f(unsigned int lo16) {
  return __builtin_bit_cast(float, lo16 << 16);
}
__device__ __forceinline__ unsigned int pkbf(float x, float y) {
  return (unsigned int)f2bf(x) | ((unsigned int)f2bf(y) << 16);
}

__device__ __forceinline__ void async_copy16(void* lds, const void* g) {
  __builtin_amdgcn_global_load_lds(
      (const __attribute__((address_space(1))) unsigned int*)g,
      (__attribute__((address_space(3))) unsigned int*)lds, 16, 0, 0);
}

// Fused packing: blocks [0, NKTOT) do E2/E1 tables for one k each,
// blocks [NKTOT, NKTOT+2048) pack A' into fragment-native layout.
__global__ __launch_bounds__(256) void pack_all(
    const float* __restrict__ input_r, const float* __restrict__ C_r,
    const float* __restrict__ angle,
    unsigned short* __restrict__ Afrag, unsigned short* __restrict__ BT,
    unsigned int* __restrict__ E1tab)
{
  int bk = blockIdx.x;
  if (bk < NKTOT) {
    int k = bk;
    int lt = threadIdx.x & 127;   // handles b = 2*lt, 2*lt+1
    int half = threadIdx.x >> 7;  // 0: E2 (angle t), 1: E1 (angle s)
    float ang = angle[k * 2 + (half ? 0 : 1)];
    int b0 = 2 * lt;
    float g0 = (float)(b0 - 128);
    float s0, c0, s1, c1;
    __sincosf(ang * g0, &s0, &c0);
    __sincosf(ang * (g0 + 1.0f), &s1, &c1);
    if (half == 0) {
      size_t r0 = (size_t)(2 * k) * LDBT;
      *(unsigned int*)(BT + r0 + b0)              = pkbf(c0, c1);
      *(unsigned int*)(BT + r0 + 256 + b0)        = pkbf(-s0, -s1);
      *(unsigned int*)(BT + r0 + LDBT + b0)       = pkbf(s0, s1);
      *(unsigned int*)(BT + r0 + LDBT + 256 + b0) = pkbf(c0, c1);
    } else {
      uint2 e;
      e.x = pkbf(c0, s0);
      e.y = pkbf(c1, s1);
      *(uint2*)(E1tab + (size_t)k * 256 + b0) = e;
    }
  } else {
    int tid = (bk - NKTOT) * 256 + threadIdx.x;
    int b = tid & 255;
    int a = (tid >> 8) & 255;
    int c = tid >> 16;
    float xr = input_r[(a * 256 + b) * 2 + 0];
    float xi = input_r[(a * 256 + b) * 2 + 1];
    size_t ci0 = ((size_t)(c * 256 + a) * 256 + b) * 2;
    float cr = C_r[ci0 + 0];
    float ci = C_r[ci0 + 1];
    float re = cr * xr - ci * xi;
    float im = cr * xi + ci * xr;
    // Afrag[((c*16+rg)*64+kc)*128 + llo*8 + j]; Re at kdim=b, Im at kdim=256+b
    size_t base = ((size_t)(c * 16 + (a >> 4)) * 64) * 128 + (size_t)(a & 15) * 8 + (b & 7);
    Afrag[base + (size_t)(b >> 3) * 128]        = f2bf(re);
    Afrag[base + (size_t)(32 + (b >> 3)) * 128] = f2bf(im);
  }
}

__global__ __launch_bounds__(256, 3) void gemm_fused(
    const unsigned short* __restrict__ Afrag,
    const unsigned short* __restrict__ BT,
    const unsigned int* __restrict__ E1tab,
    const float* __restrict__ wvec,
    float* __restrict__ out)
{
  __shared__ unsigned short Bs[64 * 64];  // 8 KB, swizzled 16B slots
  __shared__ float wavecol[4][64];

  // c = bx&7: all blocks of channel c land on one XCD -> its L2 keeps the
  // 2 MB A-slab resident for the whole kernel.
  const int bx = blockIdx.x;
  const int c = bx & 7;
  const int kt0 = (bx >> 3) * 32;  // 32 k's (64 GEMM cols) per block
  const int tid = threadIdx.x;
  const int w = tid >> 6;
  const int l = tid & 63;
  const int lhi = l >> 4;
  const int llo = l & 15;
  const int lr = l >> 3;                     // staging row within 8-row chunk
  const int lcs = ((l & 7) ^ (l >> 3)) * 8;  // staging swizzled source chunk

  // wave w owns rows w*64 .. w*64+63 -> rg = w*4 + fi
  // af[fi] at k-col kg: Aw + fi*8192 + kg*16   (contiguous 1 KB per wave)
  const unsigned short* Aw =
      Afrag + ((size_t)(c * 16 + w * 4) * 64) * 128 + lhi * 128 + llo * 8;
  const unsigned short* Bbase = BT + (size_t)(kt0 * 2) * LDBT;

  f32x4 acc[4][4];
#pragma unroll
  for (int i = 0; i < 4; ++i)
#pragma unroll
    for (int j = 0; j < 4; ++j) {
      f32x4 z = {0.f, 0.f, 0.f, 0.f};
      acc[i][j] = z;
    }

  bf16x8 af[4];
#pragma unroll
  for (int fi = 0; fi < 4; ++fi)
    af[fi] = *(const bf16x8*)(Aw + fi * 8192);
  int kg = 0;

  for (int kk = 0; kk < 512; kk += 64) {
    // stage Bs: 64 rows x 64 cols = 8 chunks of 1KB; wave w does 2
#pragma unroll
    for (int i = 0; i < 2; ++i) {
      int row0 = (w * 2 + i) * 8;
      async_copy16(&Bs[row0 * 64], Bbase + (size_t)(row0 + lr) * LDBT + kk + lcs);
    }
    __syncthreads();
#pragma unroll
    for (int kf = 0; kf < 2; ++kf) {
      const int soff = ((kf * 4 + lhi) ^ (llo & 7)) * 8;
      bf16x8 bfr[4];
#pragma unroll
      for (int fj = 0; fj < 4; ++fj)
        bfr[fj] = *(const bf16x8*)&Bs[(fj * 16 + llo) * 64 + soff];
      const int nkg = (kg + 32) & 511;
      bf16x8 afn[4];
#pragma unroll
      for (int fi = 0; fi < 4; ++fi)
        afn[fi] = *(const bf16x8*)(Aw + fi * 8192 + nkg * 16);
#pragma unroll
      for (int fi = 0; fi < 4; ++fi)
#pragma unroll
        for (int fj = 0; fj < 4; ++fj)
          acc[fi][fj] = __builtin_amdgcn_mfma_f32_16x16x32_bf16(
              af[fi], bfr[fj], acc[fi][fj], 0, 0, 0);
#pragma unroll
      for (int fi = 0; fi < 4; ++fi) af[fi] = afn[fi];
      kg = nkg;
    }
    __syncthreads();
  }

  // Epilogue: y[c,k] = sum_a E1 (*) tmp; wave w owns rows a in [w*64,w*64+64)
  // col = fj*16 + llo in [0,64); even col = Re, odd = Im of k = kt0 + col/2
#pragma unroll
  for (int fj = 0; fj < 4; ++fj) {
    const int col = fj * 16 + llo;
    const int k = kt0 + (col >> 1);
    const float sign = (col & 1) ? 1.f : -1.f;
    float sum = 0.f;
    const unsigned int* e1base = E1tab + (size_t)k * 256 + w * 64 + lhi * 4;
#pragma unroll
    for (int fi = 0; fi < 4; ++fi) {
      uint4 e4 = *(const uint4*)(e1base + fi * 16);
      unsigned int ev[4] = {e4.x, e4.y, e4.z, e4.w};
#pragma unroll
      for (int r = 0; r < 4; ++r) {
        float v = acc[fi][fj][r];        // this comp at (a, k)
        float p = __shfl_xor(v, 1, 64);  // partner comp, same (a, k)
        float er = bf2f(ev[r] & 0xFFFFu);
        float ei = bf2f(ev[r] >> 16);
        sum += er * v + sign * ei * p;   // even: er*tr - ei*ti; odd: er*ti + ei*tr
      }
    }
    sum += __shfl_xor(sum, 16, 64);
    sum += __shfl_xor(sum, 32, 64);
    if (lhi == 0) wavecol[w][col] = sum;
  }
  __syncthreads();
  if (tid < 64) {
    float sv = wavecol[0][tid] + wavecol[1][tid] + wavecol[2][tid] + wavecol[3][tid];
    int k = kt0 + (tid >> 1);
    out[((size_t)c * NKTOT + k) * 2 + (tid & 1)] = sv * wvec[k & 511];
  }
}

extern "C" void kernel_launch(void* const* d_in, const int* in_sizes, int n_in,
                              void* d_out, int out_size, void* d_ws, size_t ws_size,
                              hipStream_t stream) {
  const float* input_r = (const float*)d_in[0];  // (256,256,2)
  const float* C_r     = (const float*)d_in[1];  // (8,256,256,2)
  const float* wvec    = (const float*)d_in[2];  // (512,)
  const float* angle   = (const float*)d_in[3];  // (17408,2)
  float* out = (float*)d_out;                    // (8,17408,2)

  // workspace: Afrag (2MB) | B'T (34MB) | E1tab (17MB)
  unsigned short* Afrag = (unsigned short*)d_ws;
  unsigned short* BT    = (unsigned short*)((char*)d_ws + (size_t)2097152);
  unsigned int*   E1tab = (unsigned int*)((char*)d_ws + (size_t)2097152 + 35651584);

  pack_all<<<NKTOT + 2048, 256, 0, stream>>>(input_r, C_r, angle, Afrag, BT, E1tab);
  gemm_fused<<<8 * NBLK_K, 256, 0, stream>>>(Afrag, BT, E1tab, wvec, out);
}